// Round 1
// baseline (1276.485 us; speedup 1.0000x reference)
//
#include <hip/hip_runtime.h>

#define NN 100000
#define EE 3200000
#define HH 128
#define CC 40
#define KK 5

// ---------------------------------------------------------------- CSR build

__global__ __launch_bounds__(256) void hist_kernel(const int* __restrict__ dst,
                                                   int* __restrict__ deg) {
    int e = blockIdx.x * 256 + threadIdx.x;
    if (e < EE) atomicAdd(&deg[dst[e]], 1);
}

__global__ __launch_bounds__(256) void scan1_kernel(const int* __restrict__ deg,
                                                    int* __restrict__ partial) {
    __shared__ int sh[256];
    int t = threadIdx.x;
    int base = blockIdx.x * 1024 + t * 4;
    int s = 0;
#pragma unroll
    for (int j = 0; j < 4; ++j) {
        int idx = base + j;
        if (idx < NN) s += deg[idx];
    }
    sh[t] = s;
    __syncthreads();
    for (int off = 128; off > 0; off >>= 1) {
        if (t < off) sh[t] += sh[t + off];
        __syncthreads();
    }
    if (t == 0) partial[blockIdx.x] = sh[0];
}

__global__ void scan2_kernel(int* __restrict__ partial, int nb, int* __restrict__ offsets,
                             const float* __restrict__ hc0, const float* __restrict__ hc1,
                             float* __restrict__ wsm) {
    __shared__ int sh[128];
    int t = threadIdx.x;
    int v = (t < nb) ? partial[t] : 0;
    sh[t] = v;
    __syncthreads();
    for (int off = 1; off < 128; off <<= 1) {
        int x = (t >= off) ? sh[t - off] : 0;
        __syncthreads();
        sh[t] += x;
        __syncthreads();
    }
    if (t < nb) partial[t] = sh[t] - v;  // exclusive block offsets
    if (t == 0) {
        offsets[NN] = EE;
        for (int which = 0; which < 2; ++which) {
            const float* hc = which ? hc1 : hc0;
            float mx = hc[0];
            for (int k = 1; k < KK; ++k) mx = fmaxf(mx, hc[k]);
            float ex0 = expf(hc[0] - mx), ex1 = expf(hc[1] - mx), ex2 = expf(hc[2] - mx);
            float ex3 = expf(hc[3] - mx), ex4 = expf(hc[4] - mx);
            float sum = ex0 + ex1 + ex2 + ex3 + ex4;
            float inv = 1.0f / sum;
            wsm[which * 8 + 0] = ex0 * inv;
            wsm[which * 8 + 1] = ex1 * inv;
            wsm[which * 8 + 2] = ex2 * inv;
            wsm[which * 8 + 3] = ex3 * inv;
            wsm[which * 8 + 4] = ex4 * inv;
        }
    }
}

// degcur is read as degrees, then overwritten with the running start offsets
// (same array; per-block reads complete before writes thanks to the scan barriers).
__global__ __launch_bounds__(256) void scan3_kernel(int* degcur, const int* __restrict__ partial,
                                                    int* __restrict__ offsets) {
    __shared__ int sh[256];
    int t = threadIdx.x;
    int base = blockIdx.x * 1024 + t * 4;
    int v[4];
    int ts = 0;
#pragma unroll
    for (int j = 0; j < 4; ++j) {
        int idx = base + j;
        v[j] = (idx < NN) ? degcur[idx] : 0;
        ts += v[j];
    }
    sh[t] = ts;
    __syncthreads();
    for (int off = 1; off < 256; off <<= 1) {
        int x = (t >= off) ? sh[t - off] : 0;
        __syncthreads();
        sh[t] += x;
        __syncthreads();
    }
    int run = sh[t] - ts + partial[blockIdx.x];
#pragma unroll
    for (int j = 0; j < 4; ++j) {
        int idx = base + j;
        if (idx < NN) {
            offsets[idx] = run;
            degcur[idx] = run;  // cursor copy for the scatter pass
            run += v[j];
        }
    }
}

__global__ __launch_bounds__(256) void scatter_kernel(const int* __restrict__ src,
                                                      const int* __restrict__ dst,
                                                      const int* __restrict__ dist,
                                                      int* __restrict__ cursor,
                                                      int* __restrict__ sorted) {
    int e = blockIdx.x * 256 + threadIdx.x;
    if (e < EE) {
        int d = dst[e];
        int p = atomicAdd(&cursor[d], 1);
        sorted[p] = src[e] | (dist[e] << 20);
    }
}

// ------------------------------------------------------------------- GEMM
// U = (TRANSFORM ? relu(a*Z+d) : Z) @ W + bias, optional column sum/sumsq stats.
// Tile: 64 rows x NCOL cols, K=128 in 4 chunks of 32 staged in LDS.
// Thread t: col group c=t&15 owns cols [c*4..c*4+3] and [64+c*4..64+c*4+3]
// (split halves -> 2-way-max LDS bank aliasing); row group r=t>>4 owns 4 rows.

template <int NCOL, bool TRANSFORM, bool STATS>
__global__ __launch_bounds__(256) void gemm_kernel(const float* __restrict__ Zin,
                                                   const float* __restrict__ W,
                                                   const float* __restrict__ bias,
                                                   const float* __restrict__ ab,
                                                   float* __restrict__ Uout,
                                                   float* __restrict__ stats) {
    __shared__ float Ws[32 * NCOL + 128];
    __shared__ float Zs[64 * 132];
    __shared__ float S[16 * 128];
    int t = threadIdx.x;
    int m0 = blockIdx.x * 64;

    // stage input tile (apply previous layer's BN+ReLU on the fly if requested)
    for (int idx = t * 4; idx < 64 * 128; idx += 1024) {
        int row = idx >> 7, col = idx & 127;
        int gr = m0 + row;
        float4 v = make_float4(0.f, 0.f, 0.f, 0.f);
        if (gr < NN) v = *(const float4*)(Zin + (size_t)gr * 128 + col);
        if constexpr (TRANSFORM) {
            float4 a4 = *(const float4*)(ab + col);
            float4 d4 = *(const float4*)(ab + 128 + col);
            v.x = fmaxf(0.f, fmaf(a4.x, v.x, d4.x));
            v.y = fmaxf(0.f, fmaf(a4.y, v.y, d4.y));
            v.z = fmaxf(0.f, fmaf(a4.z, v.z, d4.z));
            v.w = fmaxf(0.f, fmaf(a4.w, v.w, d4.w));
        }
        *(float4*)(&Zs[row * 132 + col]) = v;
    }

    int c = t & 15, r = t >> 4;
    float acc0[4][4] = {};
    float acc1[4][4] = {};

    for (int kc = 0; kc < 4; ++kc) {
        __syncthreads();  // Zs ready (kc=0) / previous chunk consumed
        for (int idx = t * 4; idx < 32 * NCOL; idx += 1024)
            *(float4*)(&Ws[idx]) = *(const float4*)(W + kc * 32 * NCOL + idx);
        __syncthreads();
#pragma unroll 8
        for (int kk = 0; kk < 32; ++kk) {
            float4 w0 = *(float4*)(&Ws[kk * NCOL + c * 4]);
            float4 w1 = *(float4*)(&Ws[kk * NCOL + 64 + c * 4]);
            int k = kc * 32 + kk;
#pragma unroll
            for (int i = 0; i < 4; ++i) {
                float z = Zs[(r * 4 + i) * 132 + k];
                acc0[i][0] = fmaf(z, w0.x, acc0[i][0]);
                acc0[i][1] = fmaf(z, w0.y, acc0[i][1]);
                acc0[i][2] = fmaf(z, w0.z, acc0[i][2]);
                acc0[i][3] = fmaf(z, w0.w, acc0[i][3]);
                acc1[i][0] = fmaf(z, w1.x, acc1[i][0]);
                acc1[i][1] = fmaf(z, w1.y, acc1[i][1]);
                acc1[i][2] = fmaf(z, w1.z, acc1[i][2]);
                acc1[i][3] = fmaf(z, w1.w, acc1[i][3]);
            }
        }
    }

    bool v0 = (c * 4 < NCOL);
    bool v1 = (64 + c * 4 < NCOL);
    float4 b0 = make_float4(0.f, 0.f, 0.f, 0.f);
    float4 b1 = make_float4(0.f, 0.f, 0.f, 0.f);
    if (v0) b0 = *(const float4*)(bias + c * 4);
    if (v1) b1 = *(const float4*)(bias + 64 + c * 4);

#pragma unroll
    for (int i = 0; i < 4; ++i) {
        acc0[i][0] += b0.x; acc0[i][1] += b0.y; acc0[i][2] += b0.z; acc0[i][3] += b0.w;
        acc1[i][0] += b1.x; acc1[i][1] += b1.y; acc1[i][2] += b1.z; acc1[i][3] += b1.w;
        int row = m0 + r * 4 + i;
        if (row < NN) {
            if (v0)
                *(float4*)(Uout + (size_t)row * NCOL + c * 4) =
                    make_float4(acc0[i][0], acc0[i][1], acc0[i][2], acc0[i][3]);
            if (v1)
                *(float4*)(Uout + (size_t)row * NCOL + 64 + c * 4) =
                    make_float4(acc1[i][0], acc1[i][1], acc1[i][2], acc1[i][3]);
        }
    }

    if constexpr (STATS) {
        float* slot = stats + (blockIdx.x & 31) * 256;
        // pass 1: sums
#pragma unroll
        for (int q = 0; q < 4; ++q) {
            float s0 = 0.f, s1 = 0.f;
#pragma unroll
            for (int i = 0; i < 4; ++i) {
                if (m0 + r * 4 + i < NN) {
                    s0 += acc0[i][q];
                    s1 += acc1[i][q];
                }
            }
            S[r * 128 + c * 4 + q] = s0;
            S[r * 128 + 64 + c * 4 + q] = s1;
        }
        __syncthreads();
        if (t < 128) {
            float tot = 0.f;
#pragma unroll
            for (int rr = 0; rr < 16; ++rr) tot += S[rr * 128 + t];
            atomicAdd(slot + t, tot);
        }
        __syncthreads();
        // pass 2: sums of squares
#pragma unroll
        for (int q = 0; q < 4; ++q) {
            float s0 = 0.f, s1 = 0.f;
#pragma unroll
            for (int i = 0; i < 4; ++i) {
                if (m0 + r * 4 + i < NN) {
                    s0 += acc0[i][q] * acc0[i][q];
                    s1 += acc1[i][q] * acc1[i][q];
                }
            }
            S[r * 128 + c * 4 + q] = s0;
            S[r * 128 + 64 + c * 4 + q] = s1;
        }
        __syncthreads();
        if (t < 128) {
            float tot = 0.f;
#pragma unroll
            for (int rr = 0; rr < 16; ++rr) tot += S[rr * 128 + t];
            atomicAdd(slot + 128 + t, tot);
        }
    }
}

// ---------------------------------------------------------------- finalize
// a = g*rsqrt(var+eps); d = beta - a*mean   =>  h = relu(a*u + d)
__global__ void bn_finalize_kernel(const float* __restrict__ stats, const float* __restrict__ g,
                                   const float* __restrict__ beta, float* __restrict__ ab) {
    int ci = threadIdx.x;
    float s = 0.f, s2 = 0.f;
    for (int k = 0; k < 32; ++k) {
        s += stats[k * 256 + ci];
        s2 += stats[k * 256 + 128 + ci];
    }
    float m = s * (1.0f / NN);
    float var = s2 * (1.0f / NN) - m * m;
    float a = g[ci] * rsqrtf(var + 1e-5f);
    ab[ci] = a;
    ab[128 + ci] = beta[ci] - a * m;
}

// -------------------------------------------------------------- aggregation
// Z[i] = h(i) + sum_{e: dst=i} w[dist_e] * h(src_e),  h(j) = relu(a*U[j]+d)
__global__ __launch_bounds__(128) void agg_kernel(const float* __restrict__ U,
                                                  const int* __restrict__ offsets,
                                                  const int* __restrict__ sorted,
                                                  const float* __restrict__ ab,
                                                  const float* __restrict__ wsm,
                                                  float* __restrict__ Z) {
    __shared__ int ebuf[128];
    __shared__ float wl[8];
    int i = blockIdx.x;
    int ci = threadIdx.x;
    if (ci < KK) wl[ci] = wsm[ci];
    float a = ab[ci];
    float d = ab[128 + ci];
    int beg = offsets[i], end = offsets[i + 1];
    float acc = 0.f;
    for (int base = beg; base < end; base += 128) {
        int n = end - base;
        if (n > 128) n = 128;
        __syncthreads();  // ebuf reuse + wl visibility
        if (ci < n) ebuf[ci] = sorted[base + ci];
        __syncthreads();
        for (int j = 0; j < n; ++j) {
            int e = ebuf[j];
            int sidx = e & 0xFFFFF;
            float u = U[(size_t)sidx * 128 + ci];
            float h = fmaxf(0.f, fmaf(a, u, d));
            acc = fmaf(wl[e >> 20], h, acc);
        }
    }
    float ui = U[(size_t)i * 128 + ci];
    Z[(size_t)i * 128 + ci] = fmaxf(0.f, fmaf(a, ui, d)) + acc;
}

// ------------------------------------------------------------------ launch

extern "C" void kernel_launch(void* const* d_in, const int* in_sizes, int n_in,
                              void* d_out, int out_size, void* d_ws, size_t ws_size,
                              hipStream_t stream) {
    const float* x = (const float*)d_in[0];
    const int* ei = (const int*)d_in[1];
    const int* ed = (const int*)d_in[2];
    const float* Wi = (const float*)d_in[3];
    const float* bi = (const float*)d_in[4];
    const float* gi = (const float*)d_in[5];
    const float* bti = (const float*)d_in[6];
    const float* hc0 = (const float*)d_in[7];
    const float* W0a = (const float*)d_in[8];
    const float* b0a = (const float*)d_in[9];
    const float* g0a = (const float*)d_in[10];
    const float* bt0a = (const float*)d_in[11];
    const float* W0b = (const float*)d_in[12];
    const float* b0b = (const float*)d_in[13];
    const float* g0b = (const float*)d_in[14];
    const float* bt0b = (const float*)d_in[15];
    const float* hc1 = (const float*)d_in[16];
    const float* W1a = (const float*)d_in[17];
    const float* b1a = (const float*)d_in[18];
    const float* g1a = (const float*)d_in[19];
    const float* bt1a = (const float*)d_in[20];
    const float* W1b = (const float*)d_in[21];
    const float* b1b = (const float*)d_in[22];
    const float* g1b = (const float*)d_in[23];
    const float* bt1b = (const float*)d_in[24];
    const float* Wp1 = (const float*)d_in[25];
    const float* bp1 = (const float*)d_in[26];
    const float* gp1 = (const float*)d_in[27];
    const float* btp1 = (const float*)d_in[28];
    const float* Wp2 = (const float*)d_in[29];
    const float* bp2 = (const float*)d_in[30];
    float* out = (float*)d_out;

    const int* srcv = ei;
    const int* dstv = ei + EE;

    // workspace layout (all 16B-aligned)
    float* bufA = (float*)d_ws;                    // N*128 f32
    float* bufB = bufA + (size_t)NN * HH;          // N*128 f32
    int* sorted = (int*)(bufB + (size_t)NN * HH);  // E int
    int* offsets = sorted + EE;                    // N+1 (padded to N+4)
    int* cursor = offsets + (NN + 4);              // N int (deg -> cursor)
    float* stats = (float*)(cursor + NN);          // 6 stages * 32 slots * 256
    float* bnab = stats + 6 * 32 * 256;            // 6 stages * (a[128], d[128])
    float* wsm = bnab + 6 * 256;                   // 2 softmax weight sets (stride 8)
    int* partial = (int*)(wsm + 16);               // scan block partials

    // zero deg/cursor + stats accumulators (contiguous region)
    hipMemsetAsync(cursor, 0, (size_t)(NN + 6 * 32 * 256) * sizeof(int), stream);

    // CSR build (reused by both layers)
    hist_kernel<<<(EE + 255) / 256, 256, 0, stream>>>(dstv, cursor);
    int nb = (NN + 1023) / 1024;
    scan1_kernel<<<nb, 256, 0, stream>>>(cursor, partial);
    scan2_kernel<<<1, 128, 0, stream>>>(partial, nb, offsets, hc0, hc1, wsm);
    scan3_kernel<<<nb, 256, 0, stream>>>(cursor, partial, offsets);
    scatter_kernel<<<(EE + 255) / 256, 256, 0, stream>>>(srcv, dstv, ed, cursor, sorted);

    int gemm_grid = (NN + 63) / 64;

    // initial MLP: U1 = x @ Wi + bi -> bufA, stats stage 0
    gemm_kernel<128, false, true><<<gemm_grid, 256, 0, stream>>>(x, Wi, bi, nullptr, bufA, stats);
    bn_finalize_kernel<<<1, 128, 0, stream>>>(stats, gi, bti, bnab);

    // SPN layer 0
    agg_kernel<<<NN, 128, 0, stream>>>(bufA, offsets, sorted, bnab, wsm, bufB);
    gemm_kernel<128, false, true><<<gemm_grid, 256, 0, stream>>>(bufB, W0a, b0a, nullptr, bufA,
                                                                 stats + 1 * 32 * 256);
    bn_finalize_kernel<<<1, 128, 0, stream>>>(stats + 1 * 32 * 256, g0a, bt0a, bnab + 1 * 256);
    gemm_kernel<128, true, true><<<gemm_grid, 256, 0, stream>>>(bufA, W0b, b0b, bnab + 1 * 256,
                                                                bufB, stats + 2 * 32 * 256);
    bn_finalize_kernel<<<1, 128, 0, stream>>>(stats + 2 * 32 * 256, g0b, bt0b, bnab + 2 * 256);

    // SPN layer 1
    agg_kernel<<<NN, 128, 0, stream>>>(bufB, offsets, sorted, bnab + 2 * 256, wsm + 8, bufA);
    gemm_kernel<128, false, true><<<gemm_grid, 256, 0, stream>>>(bufA, W1a, b1a, nullptr, bufB,
                                                                 stats + 3 * 32 * 256);
    bn_finalize_kernel<<<1, 128, 0, stream>>>(stats + 3 * 32 * 256, g1a, bt1a, bnab + 3 * 256);
    gemm_kernel<128, true, true><<<gemm_grid, 256, 0, stream>>>(bufB, W1b, b1b, bnab + 3 * 256,
                                                                bufA, stats + 4 * 32 * 256);
    bn_finalize_kernel<<<1, 128, 0, stream>>>(stats + 4 * 32 * 256, g1b, bt1b, bnab + 4 * 256);

    // head
    gemm_kernel<128, true, true><<<gemm_grid, 256, 0, stream>>>(bufA, Wp1, bp1, bnab + 4 * 256,
                                                                bufB, stats + 5 * 32 * 256);
    bn_finalize_kernel<<<1, 128, 0, stream>>>(stats + 5 * 32 * 256, gp1, btp1, bnab + 5 * 256);
    gemm_kernel<40, true, false><<<gemm_grid, 256, 0, stream>>>(bufB, Wp2, bp2, bnab + 5 * 256,
                                                                out, nullptr);

    (void)in_sizes; (void)n_in; (void)out_size; (void)ws_size;
}

// Round 5
// 931.266 us; speedup vs baseline: 1.3707x; 1.3707x over previous
//
#include <hip/hip_runtime.h>

#define NN 100000
#define EE 3200000
#define HH 128
#define CC 40
#define KK 5

typedef __attribute__((ext_vector_type(8))) short bf16x8;
typedef __attribute__((ext_vector_type(4))) float f32x4;

__device__ inline float b2f(unsigned short u) {
    union { unsigned int i; float f; } c;
    c.i = ((unsigned int)u) << 16;
    return c.f;
}
__device__ inline unsigned short f2b(float f) {
    union { float f; unsigned int i; } c;
    c.f = f;
    unsigned int r = c.i + 0x7FFFu + ((c.i >> 16) & 1u);
    return (unsigned short)(r >> 16);
}

// ---------------------------------------------------------------- CSR build

__global__ __launch_bounds__(256) void hist_kernel(const int* __restrict__ dst,
                                                   int* __restrict__ deg) {
    int e = blockIdx.x * 256 + threadIdx.x;
    if (e < EE) atomicAdd(&deg[dst[e]], 1);
}

__global__ __launch_bounds__(256) void scan1_kernel(const int* __restrict__ deg,
                                                    int* __restrict__ partial) {
    __shared__ int sh[256];
    int t = threadIdx.x;
    int base = blockIdx.x * 1024 + t * 4;
    int s = 0;
#pragma unroll
    for (int j = 0; j < 4; ++j) {
        int idx = base + j;
        if (idx < NN) s += deg[idx];
    }
    sh[t] = s;
    __syncthreads();
    for (int off = 128; off > 0; off >>= 1) {
        if (t < off) sh[t] += sh[t + off];
        __syncthreads();
    }
    if (t == 0) partial[blockIdx.x] = sh[0];
}

__global__ void scan2_kernel(int* __restrict__ partial, int nb, int* __restrict__ offsets,
                             const float* __restrict__ hc0, const float* __restrict__ hc1,
                             float* __restrict__ wsm) {
    __shared__ int sh[128];
    int t = threadIdx.x;
    int v = (t < nb) ? partial[t] : 0;
    sh[t] = v;
    __syncthreads();
    for (int off = 1; off < 128; off <<= 1) {
        int x = (t >= off) ? sh[t - off] : 0;
        __syncthreads();
        sh[t] += x;
        __syncthreads();
    }
    if (t < nb) partial[t] = sh[t] - v;  // exclusive block offsets
    if (t == 0) {
        offsets[NN] = EE;
        for (int which = 0; which < 2; ++which) {
            const float* hc = which ? hc1 : hc0;
            float mx = hc[0];
            for (int k = 1; k < KK; ++k) mx = fmaxf(mx, hc[k]);
            float ex0 = expf(hc[0] - mx), ex1 = expf(hc[1] - mx), ex2 = expf(hc[2] - mx);
            float ex3 = expf(hc[3] - mx), ex4 = expf(hc[4] - mx);
            float sum = ex0 + ex1 + ex2 + ex3 + ex4;
            float inv = 1.0f / sum;
            wsm[which * 8 + 0] = ex0 * inv;
            wsm[which * 8 + 1] = ex1 * inv;
            wsm[which * 8 + 2] = ex2 * inv;
            wsm[which * 8 + 3] = ex3 * inv;
            wsm[which * 8 + 4] = ex4 * inv;
        }
    }
}

__global__ __launch_bounds__(256) void scan3_kernel(int* degcur, const int* __restrict__ partial,
                                                    int* __restrict__ offsets) {
    __shared__ int sh[256];
    int t = threadIdx.x;
    int base = blockIdx.x * 1024 + t * 4;
    int v[4];
    int ts = 0;
#pragma unroll
    for (int j = 0; j < 4; ++j) {
        int idx = base + j;
        v[j] = (idx < NN) ? degcur[idx] : 0;
        ts += v[j];
    }
    sh[t] = ts;
    __syncthreads();
    for (int off = 1; off < 256; off <<= 1) {
        int x = (t >= off) ? sh[t - off] : 0;
        __syncthreads();
        sh[t] += x;
        __syncthreads();
    }
    int run = sh[t] - ts + partial[blockIdx.x];
#pragma unroll
    for (int j = 0; j < 4; ++j) {
        int idx = base + j;
        if (idx < NN) {
            offsets[idx] = run;
            degcur[idx] = run;  // cursor copy for the scatter pass
            run += v[j];
        }
    }
}

__global__ __launch_bounds__(256) void scatter_kernel(const int* __restrict__ src,
                                                      const int* __restrict__ dst,
                                                      const int* __restrict__ dist,
                                                      int* __restrict__ cursor,
                                                      int* __restrict__ sorted) {
    int e = blockIdx.x * 256 + threadIdx.x;
    if (e < EE) {
        int d = dst[e];
        int p = atomicAdd(&cursor[d], 1);
        sorted[p] = src[e] | (dist[e] << 20);
    }
}

// ---------------------------------------------------------------- converts

__global__ __launch_bounds__(256) void convert_x_kernel(const float* __restrict__ x,
                                                        unsigned short* __restrict__ xb) {
    size_t i = (size_t)(blockIdx.x * 256 + threadIdx.x) * 4;
    float4 v = *(const float4*)(x + i);
    ushort4 o;
    o.x = f2b(v.x);
    o.y = f2b(v.y);
    o.z = f2b(v.z);
    o.w = f2b(v.w);
    *(ushort4*)(xb + i) = o;
}

// transpose + bf16-convert all 7 weights: dst[wi][n][k] = W[wi][k][n]
__global__ __launch_bounds__(256) void prep_w_kernel(const float* W0, const float* W1,
                                                     const float* W2, const float* W3,
                                                     const float* W4, const float* W5,
                                                     const float* W6,
                                                     unsigned short* __restrict__ dst) {
    int idx = blockIdx.x * 256 + threadIdx.x;
    if (idx >= 7 * 16384) return;
    int wi = idx / 16384, r = idx - wi * 16384;
    int n = r & 127, k = r >> 7;
    const float* W = wi == 0 ? W0 : wi == 1 ? W1 : wi == 2 ? W2 : wi == 3 ? W3
                   : wi == 4 ? W4 : wi == 5 ? W5 : W6;
    int ncol = (wi == 6) ? CC : 128;
    float v = (n < ncol) ? W[k * ncol + n] : 0.f;
    dst[wi * 16384 + n * 128 + k] = f2b(v);
}

// ------------------------------------------------------------------- GEMM
// U = (TRANSFORM ? relu(a*Z+d) : Z) @ W + bias  on bf16 inputs, fp32 MFMA accum.
// Block: 256 thr = 4 waves; tile 128 rows x NT*16 cols; K=128 single-shot.
// LDS: Zs[128][128] bf16, Ws[NT*16][128] bf16 (= W^T), both XOR-swizzled
// (short-index: ks ^ ((row&7)<<3)) so 16B fragment reads spread over all banks.
// Wave w owns rows [32w,32w+32): 2 m-subtiles x NT n-subtiles of 16x16x32 MFMA.
// Frag layout: A/B lane l -> row/col=l&15, k=(l>>4)*8+j ; C/D col=l&15, row=(l>>4)*4+j.

template <int NT, bool TRANSFORM, bool STATS, bool OUTF32>
__global__ __launch_bounds__(256) void mfma_gemm(const unsigned short* __restrict__ Zin,
                                                 const unsigned short* __restrict__ Wt,
                                                 const float* __restrict__ bias, int ncol_real,
                                                 const float* __restrict__ ab,
                                                 void* __restrict__ Uout,
                                                 float* __restrict__ stats) {
    __shared__ unsigned short Zs[128 * 128];
    __shared__ unsigned short Ws[NT * 16 * 128];
    int t = threadIdx.x;
    int m0 = blockIdx.x * 128;
    int c8 = t & 15;  // 16B chunk (8 bf16) within a 128-elem row

    float av[8], dv[8];
    if constexpr (TRANSFORM) {
#pragma unroll
        for (int j = 0; j < 8; ++j) {
            av[j] = ab[c8 * 8 + j];
            dv[j] = ab[128 + c8 * 8 + j];
        }
    }
    // stage A
#pragma unroll
    for (int it = 0; it < 8; ++it) {
        int chunk = it * 256 + t;
        int r = chunk >> 4;
        int gr = m0 + r;
        bf16x8 v = {};
        if (gr < NN) v = *(const bf16x8*)(Zin + (size_t)gr * 128 + c8 * 8);
        if constexpr (TRANSFORM) {
#pragma unroll
            for (int j = 0; j < 8; ++j) {
                float f = fmaxf(0.f, fmaf(av[j], b2f((unsigned short)v[j]), dv[j]));
                v[j] = (short)f2b(f);
            }
        }
        int ks = c8 * 8;
        *(bf16x8*)(&Zs[r * 128 + (ks ^ ((r & 7) << 3))]) = v;
    }
    // stage W^T
    for (int chunk = t; chunk < NT * 16 * 16; chunk += 256) {
        int r = chunk >> 4, cc = chunk & 15;
        bf16x8 v = *(const bf16x8*)(Wt + r * 128 + cc * 8);
        int ks = cc * 8;
        *(bf16x8*)(&Ws[r * 128 + (ks ^ ((r & 7) << 3))]) = v;
    }
    __syncthreads();

    int l = t & 63, w = t >> 6;
    int lr = l & 15, lg = l >> 4;

    f32x4 acc[2][NT];
#pragma unroll
    for (int mt = 0; mt < 2; ++mt)
#pragma unroll
        for (int nt = 0; nt < NT; ++nt) acc[mt][nt] = (f32x4){0.f, 0.f, 0.f, 0.f};

#pragma unroll
    for (int kc = 0; kc < 4; ++kc) {
        int ks = kc * 32 + lg * 8;
        bf16x8 afr[2];
#pragma unroll
        for (int mt = 0; mt < 2; ++mt) {
            int row = w * 32 + mt * 16 + lr;
            afr[mt] = *(const bf16x8*)(&Zs[row * 128 + (ks ^ ((row & 7) << 3))]);
        }
#pragma unroll
        for (int nt = 0; nt < NT; ++nt) {
            int n = nt * 16 + lr;
            bf16x8 bfr = *(const bf16x8*)(&Ws[n * 128 + (ks ^ ((n & 7) << 3))]);
            acc[0][nt] = __builtin_amdgcn_mfma_f32_16x16x32_bf16(afr[0], bfr, acc[0][nt], 0, 0, 0);
            acc[1][nt] = __builtin_amdgcn_mfma_f32_16x16x32_bf16(afr[1], bfr, acc[1][nt], 0, 0, 0);
        }
    }

    float bv[NT];
#pragma unroll
    for (int nt = 0; nt < NT; ++nt) {
        int col = nt * 16 + lr;
        bv[nt] = (col < ncol_real) ? bias[col] : 0.f;
    }
    float s1[NT], s2[NT];
    if constexpr (STATS) {
#pragma unroll
        for (int nt = 0; nt < NT; ++nt) { s1[nt] = 0.f; s2[nt] = 0.f; }
    }

#pragma unroll
    for (int mt = 0; mt < 2; ++mt) {
#pragma unroll
        for (int j = 0; j < 4; ++j) {
            int row = m0 + w * 32 + mt * 16 + lg * 4 + j;
            bool rv = row < NN;
#pragma unroll
            for (int nt = 0; nt < NT; ++nt) {
                float val = acc[mt][nt][j] + bv[nt];
                int col = nt * 16 + lr;
                if constexpr (STATS) {
                    if (rv) { s1[nt] += val; s2[nt] += val * val; }
                }
                if (rv && col < ncol_real) {
                    if constexpr (OUTF32)
                        ((float*)Uout)[(size_t)row * ncol_real + col] = val;
                    else
                        ((unsigned short*)Uout)[(size_t)row * 128 + col] = f2b(val);
                }
            }
        }
    }

    if constexpr (STATS) {
        float* slot = stats + (blockIdx.x & 31) * 256;
#pragma unroll
        for (int nt = 0; nt < NT; ++nt) {
            float a = s1[nt], b = s2[nt];
            a += __shfl_xor(a, 16, 64);
            b += __shfl_xor(b, 16, 64);
            a += __shfl_xor(a, 32, 64);
            b += __shfl_xor(b, 32, 64);
            if (lg == 0) {
                atomicAdd(slot + nt * 16 + lr, a);
                atomicAdd(slot + 128 + nt * 16 + lr, b);
            }
        }
    }
}

// ---------------------------------------------------------------- finalize
// a = g*rsqrt(var+eps); d = beta - a*mean   =>  h = relu(a*u + d)
__global__ void bn_finalize_kernel(const float* __restrict__ stats, const float* __restrict__ g,
                                   const float* __restrict__ beta, float* __restrict__ ab) {
    int ci = threadIdx.x;
    float s = 0.f, s2 = 0.f;
    for (int k = 0; k < 32; ++k) {
        s += stats[k * 256 + ci];
        s2 += stats[k * 256 + 128 + ci];
    }
    float m = s * (1.0f / NN);
    float var = s2 * (1.0f / NN) - m * m;
    float a = g[ci] * rsqrtf(var + 1e-5f);
    ab[ci] = a;
    ab[128 + ci] = beta[ci] - a * m;
}

// -------------------------------------------------------------- aggregation
// Z[i] = h(i) + sum_{e: dst=i} w[dist_e] * h(src_e),  h(j) = relu(a*U[j]+d)
__global__ __launch_bounds__(128) void agg_kernel(const unsigned short* __restrict__ U,
                                                  const int* __restrict__ offsets,
                                                  const int* __restrict__ sorted,
                                                  const float* __restrict__ ab,
                                                  const float* __restrict__ wsm,
                                                  unsigned short* __restrict__ Z) {
    __shared__ int ebuf[128];
    __shared__ float wl[8];
    int i = blockIdx.x;
    int ci = threadIdx.x;
    if (ci < KK) wl[ci] = wsm[ci];
    float a = ab[ci];
    float d = ab[128 + ci];
    int beg = offsets[i], end = offsets[i + 1];
    float acc = 0.f;
    for (int base = beg; base < end; base += 128) {
        int n = end - base;
        if (n > 128) n = 128;
        __syncthreads();  // ebuf reuse + wl visibility
        if (ci < n) ebuf[ci] = sorted[base + ci];
        __syncthreads();
        for (int j = 0; j < n; ++j) {
            int e = ebuf[j];
            int sidx = e & 0xFFFFF;
            float u = b2f(U[(size_t)sidx * 128 + ci]);
            float h = fmaxf(0.f, fmaf(a, u, d));
            acc = fmaf(wl[e >> 20], h, acc);
        }
    }
    float ui = b2f(U[(size_t)i * 128 + ci]);
    Z[(size_t)i * 128 + ci] = f2b(fmaxf(0.f, fmaf(a, ui, d)) + acc);
}

// ------------------------------------------------------------------ launch

extern "C" void kernel_launch(void* const* d_in, const int* in_sizes, int n_in,
                              void* d_out, int out_size, void* d_ws, size_t ws_size,
                              hipStream_t stream) {
    const float* x = (const float*)d_in[0];
    const int* ei = (const int*)d_in[1];
    const int* ed = (const int*)d_in[2];
    const float* Wi = (const float*)d_in[3];
    const float* bi = (const float*)d_in[4];
    const float* gi = (const float*)d_in[5];
    const float* bti = (const float*)d_in[6];
    const float* hc0 = (const float*)d_in[7];
    const float* W0a = (const float*)d_in[8];
    const float* b0a = (const float*)d_in[9];
    const float* g0a = (const float*)d_in[10];
    const float* bt0a = (const float*)d_in[11];
    const float* W0b = (const float*)d_in[12];
    const float* b0b = (const float*)d_in[13];
    const float* g0b = (const float*)d_in[14];
    const float* bt0b = (const float*)d_in[15];
    const float* hc1 = (const float*)d_in[16];
    const float* W1a = (const float*)d_in[17];
    const float* b1a = (const float*)d_in[18];
    const float* g1a = (const float*)d_in[19];
    const float* bt1a = (const float*)d_in[20];
    const float* W1b = (const float*)d_in[21];
    const float* b1b = (const float*)d_in[22];
    const float* g1b = (const float*)d_in[23];
    const float* bt1b = (const float*)d_in[24];
    const float* Wp1 = (const float*)d_in[25];
    const float* bp1 = (const float*)d_in[26];
    const float* gp1 = (const float*)d_in[27];
    const float* btp1 = (const float*)d_in[28];
    const float* Wp2 = (const float*)d_in[29];
    const float* bp2 = (const float*)d_in[30];
    float* out = (float*)d_out;

    const int* srcv = ei;
    const int* dstv = ei + EE;

    // workspace layout (all 16B-aligned)
    unsigned short* bufX = (unsigned short*)d_ws;            // N*128 bf16
    unsigned short* bufA = bufX + (size_t)NN * HH;           // N*128 bf16
    unsigned short* bufB = bufA + (size_t)NN * HH;           // N*128 bf16
    unsigned short* wt = bufB + (size_t)NN * HH;             // 7 * 128*128 bf16 (W^T)
    int* sorted = (int*)(wt + 7 * 16384);                    // E int
    int* offsets = sorted + EE;                              // N+1 (padded)
    int* cursor = offsets + (NN + 4);                        // N int
    float* stats = (float*)(cursor + NN);                    // 6 stages * 32 slots * 256
    float* bnab = stats + 6 * 32 * 256;                      // 6 stages * (a[128], d[128])
    float* wsm = bnab + 6 * 256;                             // 2 softmax sets (stride 8)
    int* partial = (int*)(wsm + 16);                         // scan block partials

    hipMemsetAsync(cursor, 0, (size_t)(NN + 6 * 32 * 256) * sizeof(int), stream);

    // CSR build (reused by both layers)
    hist_kernel<<<(EE + 255) / 256, 256, 0, stream>>>(dstv, cursor);
    int nb = (NN + 1023) / 1024;
    scan1_kernel<<<nb, 256, 0, stream>>>(cursor, partial);
    scan2_kernel<<<1, 128, 0, stream>>>(partial, nb, offsets, hc0, hc1, wsm);
    scan3_kernel<<<nb, 256, 0, stream>>>(cursor, partial, offsets);
    scatter_kernel<<<(EE + 255) / 256, 256, 0, stream>>>(srcv, dstv, ed, cursor, sorted);

    // bf16 conversions
    convert_x_kernel<<<(NN * HH / 4 + 255) / 256, 256, 0, stream>>>(x, bufX);
    prep_w_kernel<<<(7 * 16384 + 255) / 256, 256, 0, stream>>>(Wi, W0a, W0b, W1a, W1b, Wp1, Wp2, wt);

    int gg = (NN + 127) / 128;

    // initial MLP
    mfma_gemm<8, false, true, false><<<gg, 256, 0, stream>>>(bufX, wt, bi, 128, nullptr, bufA, stats);
    bn_finalize_kernel<<<1, 128, 0, stream>>>(stats, gi, bti, bnab);

    // SPN layer 0
    agg_kernel<<<NN, 128, 0, stream>>>(bufA, offsets, sorted, bnab, wsm, bufB);
    mfma_gemm<8, false, true, false><<<gg, 256, 0, stream>>>(bufB, wt + 16384, b0a, 128, nullptr,
                                                             bufA, stats + 8192);
    bn_finalize_kernel<<<1, 128, 0, stream>>>(stats + 8192, g0a, bt0a, bnab + 256);
    mfma_gemm<8, true, true, false><<<gg, 256, 0, stream>>>(bufA, wt + 2 * 16384, b0b, 128,
                                                            bnab + 256, bufB, stats + 2 * 8192);
    bn_finalize_kernel<<<1, 128, 0, stream>>>(stats + 2 * 8192, g0b, bt0b, bnab + 512);

    // SPN layer 1
    agg_kernel<<<NN, 128, 0, stream>>>(bufB, offsets, sorted, bnab + 512, wsm + 8, bufA);
    mfma_gemm<8, false, true, false><<<gg, 256, 0, stream>>>(bufA, wt + 3 * 16384, b1a, 128,
                                                             nullptr, bufB, stats + 3 * 8192);
    bn_finalize_kernel<<<1, 128, 0, stream>>>(stats + 3 * 8192, g1a, bt1a, bnab + 768);
    mfma_gemm<8, true, true, false><<<gg, 256, 0, stream>>>(bufB, wt + 4 * 16384, b1b, 128,
                                                            bnab + 768, bufA, stats + 4 * 8192);
    bn_finalize_kernel<<<1, 128, 0, stream>>>(stats + 4 * 8192, g1b, bt1b, bnab + 1024);

    // head
    mfma_gemm<8, true, true, false><<<gg, 256, 0, stream>>>(bufA, wt + 5 * 16384, bp1, 128,
                                                            bnab + 1024, bufB, stats + 5 * 8192);
    bn_finalize_kernel<<<1, 128, 0, stream>>>(stats + 5 * 8192, gp1, btp1, bnab + 1280);
    mfma_gemm<3, true, false, true><<<gg, 256, 0, stream>>>(bufB, wt + 6 * 16384, bp2, CC,
                                                            bnab + 1280, out, nullptr);

    (void)in_sizes; (void)n_in; (void)out_size; (void)ws_size;
}

// Round 6
// 766.859 us; speedup vs baseline: 1.6646x; 1.2144x over previous
//
#include <hip/hip_runtime.h>

#define NN 100000
#define EE 3200000
#define HH 128
#define CC 40
#define KK 5
#define NBUK 391   // ceil(NN/256) buckets of 256 nodes
#define CH 8192    // edges per coarse-scatter block

typedef __attribute__((ext_vector_type(8))) short bf16x8;
typedef __attribute__((ext_vector_type(4))) float f32x4;

__device__ inline float b2f(unsigned short u) {
    union { unsigned int i; float f; } c;
    c.i = ((unsigned int)u) << 16;
    return c.f;
}
__device__ inline unsigned short f2b(float f) {
    union { float f; unsigned int i; } c;
    c.f = f;
    unsigned int r = c.i + 0x7FFFu + ((c.i >> 16) & 1u);
    return (unsigned short)(r >> 16);
}

// ---------------------------------------------------------------- CSR build

__global__ __launch_bounds__(256) void hist_kernel(const int* __restrict__ dst,
                                                   int* __restrict__ deg) {
    int e = blockIdx.x * 256 + threadIdx.x;
    if (e < EE) atomicAdd(&deg[dst[e]], 1);
}

__global__ __launch_bounds__(256) void scan1_kernel(const int* __restrict__ deg,
                                                    int* __restrict__ partial) {
    __shared__ int sh[256];
    int t = threadIdx.x;
    int base = blockIdx.x * 1024 + t * 4;
    int s = 0;
#pragma unroll
    for (int j = 0; j < 4; ++j) {
        int idx = base + j;
        if (idx < NN) s += deg[idx];
    }
    sh[t] = s;
    __syncthreads();
    for (int off = 128; off > 0; off >>= 1) {
        if (t < off) sh[t] += sh[t + off];
        __syncthreads();
    }
    if (t == 0) partial[blockIdx.x] = sh[0];
}

__global__ void scan2_kernel(int* __restrict__ partial, int nb, int* __restrict__ offsets,
                             const float* __restrict__ hc0, const float* __restrict__ hc1,
                             float* __restrict__ wsm) {
    __shared__ int sh[128];
    int t = threadIdx.x;
    int v = (t < nb) ? partial[t] : 0;
    sh[t] = v;
    __syncthreads();
    for (int off = 1; off < 128; off <<= 1) {
        int x = (t >= off) ? sh[t - off] : 0;
        __syncthreads();
        sh[t] += x;
        __syncthreads();
    }
    if (t < nb) partial[t] = sh[t] - v;  // exclusive block offsets
    if (t == 0) {
        offsets[NN] = EE;
        for (int which = 0; which < 2; ++which) {
            const float* hc = which ? hc1 : hc0;
            float mx = hc[0];
            for (int k = 1; k < KK; ++k) mx = fmaxf(mx, hc[k]);
            float ex0 = expf(hc[0] - mx), ex1 = expf(hc[1] - mx), ex2 = expf(hc[2] - mx);
            float ex3 = expf(hc[3] - mx), ex4 = expf(hc[4] - mx);
            float sum = ex0 + ex1 + ex2 + ex3 + ex4;
            float inv = 1.0f / sum;
            wsm[which * 8 + 0] = ex0 * inv;
            wsm[which * 8 + 1] = ex1 * inv;
            wsm[which * 8 + 2] = ex2 * inv;
            wsm[which * 8 + 3] = ex3 * inv;
            wsm[which * 8 + 4] = ex4 * inv;
        }
    }
}

__global__ __launch_bounds__(256) void scan3_kernel(int* degcur, const int* __restrict__ partial,
                                                    int* __restrict__ offsets) {
    __shared__ int sh[256];
    int t = threadIdx.x;
    int base = blockIdx.x * 1024 + t * 4;
    int v[4];
    int ts = 0;
#pragma unroll
    for (int j = 0; j < 4; ++j) {
        int idx = base + j;
        v[j] = (idx < NN) ? degcur[idx] : 0;
        ts += v[j];
    }
    sh[t] = ts;
    __syncthreads();
    for (int off = 1; off < 256; off <<= 1) {
        int x = (t >= off) ? sh[t - off] : 0;
        __syncthreads();
        sh[t] += x;
        __syncthreads();
    }
    int run = sh[t] - ts + partial[blockIdx.x];
#pragma unroll
    for (int j = 0; j < 4; ++j) {
        int idx = base + j;
        if (idx < NN) {
            offsets[idx] = run;
            degcur[idx] = run;  // cursor copy for the fine scatter
            run += v[j];
        }
    }
}

__global__ __launch_bounds__(512) void bucket_init_kernel(const int* __restrict__ offsets,
                                                          int* __restrict__ gcur) {
    int b = blockIdx.x * 512 + threadIdx.x;
    if (b < NBUK) gcur[b] = offsets[b << 8];
}

// Coarse scatter: bin edges into NBUK buckets (dst>>8) with LDS staging so
// global writes are consecutive runs (line-merged) instead of random 4B.
// Payload: src(17b) | dist<<17 (3b) | (dst&255)<<20 (8b).
__global__ __launch_bounds__(512) void coarse_scatter_kernel(const int* __restrict__ src,
                                                             const int* __restrict__ dst,
                                                             const int* __restrict__ dist,
                                                             int* __restrict__ gcur,
                                                             int* __restrict__ coarse) {
    __shared__ int cnt[512];
    __shared__ int scn[512];
    __shared__ int lofs[512];
    __shared__ int gb[512];
    __shared__ int staging[CH];
    __shared__ int tgt[CH];
    int t = threadIdx.x;
    int base = blockIdx.x * CH;

    // P1: zero counters
    cnt[t] = 0;
    __syncthreads();

    // P2: load 16 edges/thread, histogram buckets, keep packed payload in regs
    int val[16], bb[16];
#pragma unroll
    for (int jj = 0; jj < 16; ++jj) {
        int e = base + jj * 512 + t;
        if (e < EE) {
            int d = dst[e];
            int b = d >> 8;
            bb[jj] = b;
            val[jj] = src[e] | (dist[e] << 17) | ((d & 255) << 20);
            atomicAdd(&cnt[b], 1);
        } else {
            bb[jj] = -1;
            val[jj] = 0;
        }
    }
    __syncthreads();

    // P3: inclusive scan of cnt -> scn; exclusive into lofs; global bases into gb
    int c = cnt[t];
    scn[t] = c;
    __syncthreads();
    for (int off = 1; off < 512; off <<= 1) {
        int x = (t >= off) ? scn[t - off] : 0;
        __syncthreads();
        scn[t] += x;
        __syncthreads();
    }
    lofs[t] = scn[t] - c;
    if (t < NBUK && c > 0) gb[t] = atomicAdd(&gcur[t], c);
    cnt[t] = 0;  // reuse as second counter
    __syncthreads();

    // P4: place into LDS staging (bucket-grouped) + record global target
#pragma unroll
    for (int jj = 0; jj < 16; ++jj) {
        int b = bb[jj];
        if (b >= 0) {
            int pos = atomicAdd(&cnt[b], 1);
            int slot = lofs[b] + pos;
            staging[slot] = val[jj];
            tgt[slot] = gb[b] + pos;
        }
    }
    __syncthreads();

    // P5: write out; consecutive slots within a bucket segment -> consecutive
    // global addresses -> line-merged write-back
    int total = scn[511];
    for (int j = t; j < total; j += 512) coarse[tgt[j]] = staging[j];
}

// Fine scatter: one block per bucket; reads its coarse segment sequentially,
// scatters within the bucket's (L2-resident) output window to final CSR order.
__global__ __launch_bounds__(512) void fine_scatter_kernel(const int* __restrict__ coarse,
                                                           const int* __restrict__ offsets,
                                                           int* __restrict__ cursor,
                                                           int* __restrict__ sorted) {
    int b = blockIdx.x;
    int gstart = offsets[b << 8];
    int nend = (b + 1) << 8;
    int gend = (nend >= NN) ? EE : offsets[nend];
    for (int idx = gstart + threadIdx.x; idx < gend; idx += 512) {
        int v = coarse[idx];
        int d = (b << 8) | ((v >> 20) & 255);
        int p = atomicAdd(&cursor[d], 1);
        sorted[p] = (v & 0x1FFFF) | (((v >> 17) & 7) << 20);  // src | dist<<20
    }
}

// ---------------------------------------------------------------- converts

__global__ __launch_bounds__(256) void convert_x_kernel(const float* __restrict__ x,
                                                        unsigned short* __restrict__ xb) {
    size_t i = (size_t)(blockIdx.x * 256 + threadIdx.x) * 4;
    float4 v = *(const float4*)(x + i);
    ushort4 o;
    o.x = f2b(v.x);
    o.y = f2b(v.y);
    o.z = f2b(v.z);
    o.w = f2b(v.w);
    *(ushort4*)(xb + i) = o;
}

// transpose + bf16-convert all 7 weights: dst[wi][n][k] = W[wi][k][n]
__global__ __launch_bounds__(256) void prep_w_kernel(const float* W0, const float* W1,
                                                     const float* W2, const float* W3,
                                                     const float* W4, const float* W5,
                                                     const float* W6,
                                                     unsigned short* __restrict__ dst) {
    int idx = blockIdx.x * 256 + threadIdx.x;
    if (idx >= 7 * 16384) return;
    int wi = idx / 16384, r = idx - wi * 16384;
    int n = r & 127, k = r >> 7;
    const float* W = wi == 0 ? W0 : wi == 1 ? W1 : wi == 2 ? W2 : wi == 3 ? W3
                   : wi == 4 ? W4 : wi == 5 ? W5 : W6;
    int ncol = (wi == 6) ? CC : 128;
    float v = (n < ncol) ? W[k * ncol + n] : 0.f;
    dst[wi * 16384 + n * 128 + k] = f2b(v);
}

// ------------------------------------------------------------------- GEMM
// U = (TRANSFORM ? relu(a*Z+d) : Z) @ W + bias  on bf16 inputs, fp32 MFMA accum.

template <int NT, bool TRANSFORM, bool STATS, bool OUTF32>
__global__ __launch_bounds__(256) void mfma_gemm(const unsigned short* __restrict__ Zin,
                                                 const unsigned short* __restrict__ Wt,
                                                 const float* __restrict__ bias, int ncol_real,
                                                 const float* __restrict__ ab,
                                                 void* __restrict__ Uout,
                                                 float* __restrict__ stats) {
    __shared__ unsigned short Zs[128 * 128];
    __shared__ unsigned short Ws[NT * 16 * 128];
    int t = threadIdx.x;
    int m0 = blockIdx.x * 128;
    int c8 = t & 15;  // 16B chunk (8 bf16) within a 128-elem row

    float av[8], dv[8];
    if constexpr (TRANSFORM) {
#pragma unroll
        for (int j = 0; j < 8; ++j) {
            av[j] = ab[c8 * 8 + j];
            dv[j] = ab[128 + c8 * 8 + j];
        }
    }
    // stage A
#pragma unroll
    for (int it = 0; it < 8; ++it) {
        int chunk = it * 256 + t;
        int r = chunk >> 4;
        int gr = m0 + r;
        bf16x8 v = {};
        if (gr < NN) v = *(const bf16x8*)(Zin + (size_t)gr * 128 + c8 * 8);
        if constexpr (TRANSFORM) {
#pragma unroll
            for (int j = 0; j < 8; ++j) {
                float f = fmaxf(0.f, fmaf(av[j], b2f((unsigned short)v[j]), dv[j]));
                v[j] = (short)f2b(f);
            }
        }
        int ks = c8 * 8;
        *(bf16x8*)(&Zs[r * 128 + (ks ^ ((r & 7) << 3))]) = v;
    }
    // stage W^T
    for (int chunk = t; chunk < NT * 16 * 16; chunk += 256) {
        int r = chunk >> 4, cc = chunk & 15;
        bf16x8 v = *(const bf16x8*)(Wt + r * 128 + cc * 8);
        int ks = cc * 8;
        *(bf16x8*)(&Ws[r * 128 + (ks ^ ((r & 7) << 3))]) = v;
    }
    __syncthreads();

    int l = t & 63, w = t >> 6;
    int lr = l & 15, lg = l >> 4;

    f32x4 acc[2][NT];
#pragma unroll
    for (int mt = 0; mt < 2; ++mt)
#pragma unroll
        for (int nt = 0; nt < NT; ++nt) acc[mt][nt] = (f32x4){0.f, 0.f, 0.f, 0.f};

#pragma unroll
    for (int kc = 0; kc < 4; ++kc) {
        int ks = kc * 32 + lg * 8;
        bf16x8 afr[2];
#pragma unroll
        for (int mt = 0; mt < 2; ++mt) {
            int row = w * 32 + mt * 16 + lr;
            afr[mt] = *(const bf16x8*)(&Zs[row * 128 + (ks ^ ((row & 7) << 3))]);
        }
#pragma unroll
        for (int nt = 0; nt < NT; ++nt) {
            int n = nt * 16 + lr;
            bf16x8 bfr = *(const bf16x8*)(&Ws[n * 128 + (ks ^ ((n & 7) << 3))]);
            acc[0][nt] = __builtin_amdgcn_mfma_f32_16x16x32_bf16(afr[0], bfr, acc[0][nt], 0, 0, 0);
            acc[1][nt] = __builtin_amdgcn_mfma_f32_16x16x32_bf16(afr[1], bfr, acc[1][nt], 0, 0, 0);
        }
    }

    float bv[NT];
#pragma unroll
    for (int nt = 0; nt < NT; ++nt) {
        int col = nt * 16 + lr;
        bv[nt] = (col < ncol_real) ? bias[col] : 0.f;
    }
    float s1[NT], s2[NT];
    if constexpr (STATS) {
#pragma unroll
        for (int nt = 0; nt < NT; ++nt) { s1[nt] = 0.f; s2[nt] = 0.f; }
    }

#pragma unroll
    for (int mt = 0; mt < 2; ++mt) {
#pragma unroll
        for (int j = 0; j < 4; ++j) {
            int row = m0 + w * 32 + mt * 16 + lg * 4 + j;
            bool rv = row < NN;
#pragma unroll
            for (int nt = 0; nt < NT; ++nt) {
                float val = acc[mt][nt][j] + bv[nt];
                int col = nt * 16 + lr;
                if constexpr (STATS) {
                    if (rv) { s1[nt] += val; s2[nt] += val * val; }
                }
                if (rv && col < ncol_real) {
                    if constexpr (OUTF32)
                        ((float*)Uout)[(size_t)row * ncol_real + col] = val;
                    else
                        ((unsigned short*)Uout)[(size_t)row * 128 + col] = f2b(val);
                }
            }
        }
    }

    if constexpr (STATS) {
        float* slot = stats + (blockIdx.x & 31) * 256;
#pragma unroll
        for (int nt = 0; nt < NT; ++nt) {
            float a = s1[nt], b = s2[nt];
            a += __shfl_xor(a, 16, 64);
            b += __shfl_xor(b, 16, 64);
            a += __shfl_xor(a, 32, 64);
            b += __shfl_xor(b, 32, 64);
            if (lg == 0) {
                atomicAdd(slot + nt * 16 + lr, a);
                atomicAdd(slot + 128 + nt * 16 + lr, b);
            }
        }
    }
}

// ---------------------------------------------------------------- finalize
// a = g*rsqrt(var+eps); d = beta - a*mean   =>  h = relu(a*u + d)
__global__ void bn_finalize_kernel(const float* __restrict__ stats, const float* __restrict__ g,
                                   const float* __restrict__ beta, float* __restrict__ ab) {
    int ci = threadIdx.x;
    float s = 0.f, s2 = 0.f;
    for (int k = 0; k < 32; ++k) {
        s += stats[k * 256 + ci];
        s2 += stats[k * 256 + 128 + ci];
    }
    float m = s * (1.0f / NN);
    float var = s2 * (1.0f / NN) - m * m;
    float a = g[ci] * rsqrtf(var + 1e-5f);
    ab[ci] = a;
    ab[128 + ci] = beta[ci] - a * m;
}

// -------------------------------------------------------------- aggregation
// Z[i] = h(i) + sum_{e: dst=i} w[dist_e] * h(src_e),  h(j) = relu(a*U[j]+d)
__global__ __launch_bounds__(128) void agg_kernel(const unsigned short* __restrict__ U,
                                                  const int* __restrict__ offsets,
                                                  const int* __restrict__ sorted,
                                                  const float* __restrict__ ab,
                                                  const float* __restrict__ wsm,
                                                  unsigned short* __restrict__ Z) {
    __shared__ int ebuf[128];
    __shared__ float wl[8];
    int i = blockIdx.x;
    int ci = threadIdx.x;
    if (ci < KK) wl[ci] = wsm[ci];
    float a = ab[ci];
    float d = ab[128 + ci];
    int beg = offsets[i], end = offsets[i + 1];
    float acc = 0.f;
    for (int base = beg; base < end; base += 128) {
        int n = end - base;
        if (n > 128) n = 128;
        __syncthreads();  // ebuf reuse + wl visibility
        if (ci < n) ebuf[ci] = sorted[base + ci];
        __syncthreads();
        for (int j = 0; j < n; ++j) {
            int e = ebuf[j];
            int sidx = e & 0xFFFFF;
            float u = b2f(U[(size_t)sidx * 128 + ci]);
            float h = fmaxf(0.f, fmaf(a, u, d));
            acc = fmaf(wl[e >> 20], h, acc);
        }
    }
    float ui = b2f(U[(size_t)i * 128 + ci]);
    Z[(size_t)i * 128 + ci] = f2b(fmaxf(0.f, fmaf(a, ui, d)) + acc);
}

// ------------------------------------------------------------------ launch

extern "C" void kernel_launch(void* const* d_in, const int* in_sizes, int n_in,
                              void* d_out, int out_size, void* d_ws, size_t ws_size,
                              hipStream_t stream) {
    const float* x = (const float*)d_in[0];
    const int* ei = (const int*)d_in[1];
    const int* ed = (const int*)d_in[2];
    const float* Wi = (const float*)d_in[3];
    const float* bi = (const float*)d_in[4];
    const float* gi = (const float*)d_in[5];
    const float* bti = (const float*)d_in[6];
    const float* hc0 = (const float*)d_in[7];
    const float* W0a = (const float*)d_in[8];
    const float* b0a = (const float*)d_in[9];
    const float* g0a = (const float*)d_in[10];
    const float* bt0a = (const float*)d_in[11];
    const float* W0b = (const float*)d_in[12];
    const float* b0b = (const float*)d_in[13];
    const float* g0b = (const float*)d_in[14];
    const float* bt0b = (const float*)d_in[15];
    const float* hc1 = (const float*)d_in[16];
    const float* W1a = (const float*)d_in[17];
    const float* b1a = (const float*)d_in[18];
    const float* g1a = (const float*)d_in[19];
    const float* bt1a = (const float*)d_in[20];
    const float* W1b = (const float*)d_in[21];
    const float* b1b = (const float*)d_in[22];
    const float* g1b = (const float*)d_in[23];
    const float* bt1b = (const float*)d_in[24];
    const float* Wp1 = (const float*)d_in[25];
    const float* bp1 = (const float*)d_in[26];
    const float* gp1 = (const float*)d_in[27];
    const float* btp1 = (const float*)d_in[28];
    const float* Wp2 = (const float*)d_in[29];
    const float* bp2 = (const float*)d_in[30];
    float* out = (float*)d_out;

    const int* srcv = ei;
    const int* dstv = ei + EE;

    // workspace layout (all 16B-aligned)
    unsigned short* bufX = (unsigned short*)d_ws;            // N*128 bf16
    unsigned short* bufA = bufX + (size_t)NN * HH;           // N*128 bf16
    unsigned short* bufB = bufA + (size_t)NN * HH;           // N*128 bf16
    unsigned short* wt = bufB + (size_t)NN * HH;             // 7 * 128*128 bf16 (W^T)
    int* sorted = (int*)(wt + 7 * 16384);                    // E int
    int* coarse = sorted + EE;                               // E int (bucketed)
    int* offsets = coarse + EE;                              // N+1 (padded)
    int* cursor = offsets + (NN + 4);                        // N int
    float* stats = (float*)(cursor + NN);                    // 6 stages * 32 slots * 256
    float* bnab = stats + 6 * 32 * 256;                      // 6 stages * (a[128], d[128])
    float* wsm = bnab + 6 * 256;                             // 2 softmax sets (stride 8)
    int* gcur = (int*)(wsm + 16);                            // NBUK bucket cursors
    int* partial = gcur + ((NBUK + 3) & ~3);                 // scan block partials

    hipMemsetAsync(cursor, 0, (size_t)(NN + 6 * 32 * 256) * sizeof(int), stream);

    // CSR build (reused by both layers)
    hist_kernel<<<(EE + 255) / 256, 256, 0, stream>>>(dstv, cursor);
    int nb = (NN + 1023) / 1024;
    scan1_kernel<<<nb, 256, 0, stream>>>(cursor, partial);
    scan2_kernel<<<1, 128, 0, stream>>>(partial, nb, offsets, hc0, hc1, wsm);
    scan3_kernel<<<nb, 256, 0, stream>>>(cursor, partial, offsets);
    bucket_init_kernel<<<1, 512, 0, stream>>>(offsets, gcur);
    coarse_scatter_kernel<<<(EE + CH - 1) / CH, 512, 0, stream>>>(srcv, dstv, ed, gcur, coarse);
    fine_scatter_kernel<<<NBUK, 512, 0, stream>>>(coarse, offsets, cursor, sorted);

    // bf16 conversions
    convert_x_kernel<<<(NN * HH / 4 + 255) / 256, 256, 0, stream>>>(x, bufX);
    prep_w_kernel<<<(7 * 16384 + 255) / 256, 256, 0, stream>>>(Wi, W0a, W0b, W1a, W1b, Wp1, Wp2, wt);

    int gg = (NN + 127) / 128;

    // initial MLP
    mfma_gemm<8, false, true, false><<<gg, 256, 0, stream>>>(bufX, wt, bi, 128, nullptr, bufA, stats);
    bn_finalize_kernel<<<1, 128, 0, stream>>>(stats, gi, bti, bnab);

    // SPN layer 0
    agg_kernel<<<NN, 128, 0, stream>>>(bufA, offsets, sorted, bnab, wsm, bufB);
    mfma_gemm<8, false, true, false><<<gg, 256, 0, stream>>>(bufB, wt + 16384, b0a, 128, nullptr,
                                                             bufA, stats + 8192);
    bn_finalize_kernel<<<1, 128, 0, stream>>>(stats + 8192, g0a, bt0a, bnab + 256);
    mfma_gemm<8, true, true, false><<<gg, 256, 0, stream>>>(bufA, wt + 2 * 16384, b0b, 128,
                                                            bnab + 256, bufB, stats + 2 * 8192);
    bn_finalize_kernel<<<1, 128, 0, stream>>>(stats + 2 * 8192, g0b, bt0b, bnab + 512);

    // SPN layer 1
    agg_kernel<<<NN, 128, 0, stream>>>(bufB, offsets, sorted, bnab + 512, wsm + 8, bufA);
    mfma_gemm<8, false, true, false><<<gg, 256, 0, stream>>>(bufA, wt + 3 * 16384, b1a, 128,
                                                             nullptr, bufB, stats + 3 * 8192);
    bn_finalize_kernel<<<1, 128, 0, stream>>>(stats + 3 * 8192, g1a, bt1a, bnab + 768);
    mfma_gemm<8, true, true, false><<<gg, 256, 0, stream>>>(bufB, wt + 4 * 16384, b1b, 128,
                                                            bnab + 768, bufA, stats + 4 * 8192);
    bn_finalize_kernel<<<1, 128, 0, stream>>>(stats + 4 * 8192, g1b, bt1b, bnab + 1024);

    // head
    mfma_gemm<8, true, true, false><<<gg, 256, 0, stream>>>(bufA, wt + 5 * 16384, bp1, 128,
                                                            bnab + 1024, bufB, stats + 5 * 8192);
    bn_finalize_kernel<<<1, 128, 0, stream>>>(stats + 5 * 8192, gp1, btp1, bnab + 1280);
    mfma_gemm<3, true, false, true><<<gg, 256, 0, stream>>>(bufB, wt + 6 * 16384, bp2, CC,
                                                            bnab + 1280, out, nullptr);

    (void)in_sizes; (void)n_in; (void)out_size; (void)ws_size;
}